// Round 5
// baseline (1059.305 us; speedup 1.0000x reference)
//
#include <hip/hip_runtime.h>

#define NGRID 128
#define NPTS  (NGRID * NGRID * NGRID)   // 2,097,152 points
#define NDIR  128                        // directions
#define NK    25                         // SH bases
#define PI_SRC 3.1415926f

// bf16x2 pack/unpack (bf16 keeps fp32 exponent range: no denormal flush for
// the tiny Gaussian tail weights, unlike fp16; 4e-3 rel err vanishes in log).
__device__ __forceinline__ unsigned int pack_bf16x2(float a, float b) {
    unsigned int ua = __float_as_uint(a);
    unsigned int ub = __float_as_uint(b);
    ua += 0x7FFFu + ((ua >> 16) & 1u);   // round to nearest even
    ub += 0x7FFFu + ((ub >> 16) & 1u);
    return (ua >> 16) | (ub & 0xFFFF0000u);
}
__device__ __forceinline__ float2 unpack_bf16x2(unsigned int v) {
    return make_float2(__uint_as_float(v << 16),
                       __uint_as_float(v & 0xFFFF0000u));
}

// One thread per volume point. Pass 1: compute unnormalized weights e[d] for
// all 128 directions (dot -> clip -> acos -> exp * sinth), accumulate sum,
// stash e[d] bf16-packed in LDS ([pair][tid] layout: bank-conflict-free).
// Pass 2: v[d] = log(1e-4 + e[d] * 4/(sum*norm2)), accumulate 25 SH
// projections in registers (bases read via wave-uniform scalar loads).
__global__ __launch_bounds__(256, 2)
void sh_nearfield_kernel(const float* __restrict__ bases,
                         const float* __restrict__ th,
                         const float* __restrict__ ph,
                         const int*   __restrict__ iternum,
                         int B,
                         float* __restrict__ out) {
    __shared__ float4       s_vec[NDIR];          // (vx, vy, vz, sinth)
    __shared__ unsigned int s_l0[NDIR / 2][256];  // bf16x2, 64 KB

    const int tid = threadIdx.x;
    const int b   = blockIdx.y;

    // --- per-block setup: direction vectors ---
    if (tid < NDIR) {
        float t  = th[tid];
        float p  = ph[tid];
        float st = sinf(t), ct = cosf(t);
        float sp = sinf(p), cp = cosf(p);
        s_vec[tid] = make_float4(st * sp, ct, st * cp, st);
    }
    __syncthreads();

    // --- light position (mirrors reference ph0 arithmetic, fp32) ---
    float ph0 = ((float)(iternum[0] * B + b) * 2.0f * PI_SRC) / 131.0f;
    const float lx = sinf(ph0) * 0.3f;
    const float ly = 0.0f;
    const float lz = 0.4f;

    // --- this thread's grid point (x fastest per meshgrid 'ij' flat order) ---
    const int p  = blockIdx.x * 256 + tid;
    const int ix = p & (NGRID - 1);
    const int iy = (p >> 7) & (NGRID - 1);
    const int iz = p >> 14;
    const float step = 2.0f / 127.0f;
    const float fx = fmaf((float)ix, step, -1.0f);
    const float fy = fmaf((float)iy, step, -1.0f);
    const float fz = fmaf((float)iz, step, -1.0f);

    const float dx = lx - fx, dy = ly - fy, dz = lz - fz;
    const float norm2 = fmaf(dx, dx, fmaf(dy, dy, fmaf(dz, dz, 1e-4f)));
    const float invn  = rsqrtf(norm2);
    const float nx = dx * invn, ny = dy * invn, nz = dz * invn;

    // --- pass 1: weights, sum ---
    float sum = 0.0f;
    #pragma unroll 4
    for (int pr = 0; pr < NDIR / 2; ++pr) {
        const float4 v0 = s_vec[2 * pr + 0];
        const float4 v1 = s_vec[2 * pr + 1];
        float dp0 = fmaf(v0.x, nx, fmaf(v0.y, ny, v0.z * nz));
        float dp1 = fmaf(v1.x, nx, fmaf(v1.y, ny, v1.z * nz));
        dp0 = fminf(fmaxf(dp0, -0.999f), 0.999f);
        dp1 = fminf(fmaxf(dp1, -0.999f), 0.999f);
        const float t0 = acosf(dp0);
        const float t1 = acosf(dp1);
        const float e0 = __expf(-16.0f * t0 * t0) * v0.w;
        const float e1 = __expf(-16.0f * t1 * t1) * v1.w;
        sum += e0 + e1;
        s_l0[pr][tid] = pack_bf16x2(e0, e1);
    }

    // --- pass 2: log + SH projection ---
    const float c = 4.0f / (sum * norm2);
    float acc[NK];
    #pragma unroll
    for (int k = 0; k < NK; ++k) acc[k] = 0.0f;

    #pragma unroll 2
    for (int pr = 0; pr < NDIR / 2; ++pr) {
        const float2 e = unpack_bf16x2(s_l0[pr][tid]);
        const float v0l = __logf(fmaf(e.x, c, 1e-4f));
        const float v1l = __logf(fmaf(e.y, c, 1e-4f));
        #pragma unroll
        for (int k = 0; k < NK; ++k) {
            const float b0 = bases[k * NDIR + 2 * pr];
            const float b1 = bases[k * NDIR + 2 * pr + 1];
            acc[k] = fmaf(b0, v0l, fmaf(b1, v1l, acc[k]));
        }
    }

    // --- epilogue: scale + write 3 identical channels per basis (streaming) ---
    const float scale = (float)(9.869604401089358 / 128.0);  // pi^2 / (2*L*L)
    const size_t base_off = (size_t)b * (3 * NK) * NPTS + (size_t)p;
    #pragma unroll
    for (int k = 0; k < NK; ++k) {
        const float r = acc[k] * scale;
        float* o = out + (size_t)(3 * k) * NPTS + base_off;
        __builtin_nontemporal_store(r, o);
        __builtin_nontemporal_store(r, o + NPTS);
        __builtin_nontemporal_store(r, o + 2 * (size_t)NPTS);
    }
}

extern "C" void kernel_launch(void* const* d_in, const int* in_sizes, int n_in,
                              void* d_out, int out_size, void* d_ws, size_t ws_size,
                              hipStream_t stream) {
    const float* bases   = (const float*)d_in[0];
    const float* th      = (const float*)d_in[1];
    const float* ph      = (const float*)d_in[2];
    const int*   iternum = (const int*)d_in[3];
    const int    B       = in_sizes[4];   // lightid.shape[0]
    float* out = (float*)d_out;

    dim3 grid(NPTS / 256, B, 1);
    sh_nearfield_kernel<<<grid, 256, 0, stream>>>(bases, th, ph, iternum, B, out);
}